// Round 19
// baseline (215.262 us; speedup 1.0000x reference)
//
#include <hip/hip_runtime.h>

// Problem constants
#define N_NODES 8192
#define N_EDGES 65536

typedef __attribute__((ext_vector_type(8))) short bf16x8;
typedef __attribute__((ext_vector_type(4))) float f32x4;

// ---------- bf16 helpers (OCP bf16 = top 16 bits of f32, RNE) ----------
static __device__ __forceinline__ float bfl(unsigned v){ unsigned u=v<<16; float f; __builtin_memcpy(&f,&u,4); return f; }
static __device__ __forceinline__ float bfh(unsigned v){ unsigned u=v&0xffff0000u; float f; __builtin_memcpy(&f,&u,4); return f; }
static __device__ __forceinline__ unsigned short f2bf(float f){ unsigned u; __builtin_memcpy(&u,&f,4); u += 0x7fffu + ((u>>16)&1u); return (unsigned short)(u>>16); }
static __device__ __forceinline__ unsigned pk(float a, float b){ return (unsigned)f2bf(a) | ((unsigned)f2bf(b)<<16); }
static __device__ __forceinline__ float silu_f(float v){ return v/(1.f+__expf(-v)); }

// ---------- K_prep: fused {linup | wmlp | wtf(serial) | wwf | count} by block range ----------
__global__ __launch_bounds__(256) void k_prep(
    const float* __restrict__ nf,  const float* __restrict__ wup,  float* __restrict__ x,
    const float* __restrict__ wr0, const float* __restrict__ wr1,  const float* __restrict__ wr2,
    unsigned short* __restrict__ w0f, unsigned short* __restrict__ w1f, unsigned short* __restrict__ w2f,
    const float* __restrict__ wr3, const float* __restrict__ wtr,  unsigned short* __restrict__ wtf,
    const float* __restrict__ wlin, const float* __restrict__ wmlin,
    const float* __restrict__ wskip, const float* __restrict__ wmskip, unsigned* __restrict__ wwf,
    const int* __restrict__ recv, int* __restrict__ cnt)
{
    const int bid=blockIdx.x, t=threadIdx.x;
    if(bid<2048){
        // ---- linup: x = nf @ wup / 8 ----
        __shared__ float s[4][64];
        const int wv=t>>6, lane=t&63;
        const int n=bid*4+wv;
        s[wv][lane]=nf[(size_t)n*64+lane];
        __syncthreads();
        float acc=0.f;
        for(int c=0;c<64;++c) acc += s[wv][c]*wup[c*64+lane];
        x[(size_t)n*64+lane]=acc*0.125f;
    } else if(bid<2068){
        // ---- wmlp: MLP weight fragment tables ----
        const int b=bid-2048;
        #pragma unroll
        for(int z=0;z<2;++z){
            int idx=t*2+z;
            int lane=idx>>3, i=idx&7;
            if(b<4){
                int nt=b, k=(lane>>4)*8+i, n=nt*16+(lane&15);
                float v=(k<16)? wr0[k*64+n]*0.25f : 0.f;
                w0f[(nt*64+lane)*8+i]=f2bf(v);
            } else if(b<12){
                int q=b-4, nt=q>>1, ks=q&1;
                int k=ks*32+(lane>>4)*8+i, n=nt*16+(lane&15);
                w1f[((nt*2+ks)*64+lane)*8+i]=f2bf(wr1[k*64+n]*0.125f);
            } else {
                int q=b-12, nt=q>>1, ks=q&1;
                int k=ks*32+(lane>>4)*8+i, n=nt*16+(lane&15);
                w2f[((nt*2+ks)*64+lane)*8+i]=f2bf(wr2[k*64+n]*0.125f);
            }
        }
    } else if(bid<2132){
        // ---- wtf (serial GEMV variant; hidden under the other blocks) ----
        const int b=bid-2068;          // 0..63 = mt*2+ks
        const int mt=b>>1, ks=b&1;
        #pragma unroll
        for(int z=0;z<2;++z){
            int idx=t*2+z;
            int lane=idx>>3, i=idx&7;
            int k=ks*32+(lane>>4)*8+i;
            int n=mt*16+(lane&15);
            int j=n>>3, s=n&7;
            float v;
            if(s<4) v=wr3[k*256+s*64+j]*0.125f;
            else {
                float acc=0.f;
                for(int kk=0;kk<256;++kk) acc+=wr3[k*256+kk]*wtr[kk*256+(s-4)*64+j];
                v=acc*(1.f/128.f);
            }
            wtf[((size_t)b*64+lane)*8+i]=f2bf(v);
        }
    } else if(bid<2644){
        // ---- wwf: node-contraction fragment table ----
        const int b=bid-2132, ten=b>>8, lc=b&255, l=lc>>6, c=lc&63;
        const float* WL = ten? wmlin:wlin;
        const float* WS = ten? wmskip:wskip;
        const float scale = ten? (1.f/4096.f):(1.f/256.f);
        const int wg=t>>6, s=t&63, lane=s>>1, half=s&1;
        const int w=wg*16+(lane&15);
        const int v0=(lane>>4)*8+half*4;
        float a0=0,a1=0,a2=0,a3=0;
        for(int u=0;u<64;++u){
            float wl=WL[(l*64+c)*64+u];
            const float* wsp=&WS[(((l*64+u)*16+v0)*64)+w];
            a0+=wl*wsp[0]; a1+=wl*wsp[64]; a2+=wl*wsp[128]; a3+=wl*wsp[192];
        }
        size_t fi=(((size_t)ten*4+l)*64+c)*4+wg;
        unsigned* op=wwf + (fi*32+lane)*4 + half*2;
        op[0]=pk(a0*scale,a1*scale); op[1]=pk(a2*scale,a3*scale);
    } else {
        // ---- count ----
        int e=(bid-2644)*256+t;
        atomicAdd(&cnt[recv[e]],1);
    }
}

// ---------- k_scan ----------
__global__ __launch_bounds__(1024) void k_scan(const int* __restrict__ cnt, int* __restrict__ rowptr, int* __restrict__ cur){
    __shared__ int s[1024];
    const int t=threadIdx.x;
    int c[8]; int sum=0;
    #pragma unroll
    for(int i=0;i<8;++i){ c[i]=cnt[t*8+i]; sum+=c[i]; }
    s[t]=sum; __syncthreads();
    for(int off=1;off<1024;off<<=1){
        int v=s[t]; int add=(t>=off)? s[t-off]:0;
        __syncthreads();
        s[t]=v+add;
        __syncthreads();
    }
    int run=s[t]-sum;
    #pragma unroll
    for(int i=0;i<8;++i){ rowptr[t*8+i]=run; cur[t*8+i]=run; run+=c[i]; }
    if(t==1023) rowptr[8192]=run;
}

// ---------- K_mid: fused {scatter | edge2} by block range ----------
__global__ __launch_bounds__(256) void k_mid(
    const int* __restrict__ recv, int* __restrict__ cur, int* __restrict__ elist,
    const float* __restrict__ ef, const float* __restrict__ mminv,
    const int* __restrict__ sender,
    const float* __restrict__ wdens,
    const uint4* __restrict__ w0f, const uint4* __restrict__ w1f,
    const uint4* __restrict__ w2f, const uint4* __restrict__ wtf,
    const float* __restrict__ x,
    unsigned short* __restrict__ wxc, float* __restrict__ ed)
{
    __shared__ unsigned short hA[4096];   // 8KB  [e][k] bf16 swizzled
    __shared__ unsigned short hB[4096];   // 8KB
    __shared__ float xs[64*68];           // 17KB [e][j pad 68]
    const int bid=blockIdx.x, t=threadIdx.x;
    if(bid<256){
        // ---- scatter ----
        int e=bid*256+t;
        int r=recv[e];
        int p=atomicAdd(&cur[r],1);
        elist[p]=e;
        return;
    }
    // ---- edge2 ----
    const int lane=t&63, wv=t>>6;
    const int tile=(bid-256)*64;

    {
        const int e=t>>2, q=t&3, ge=tile+e;
        const int s=sender[ge];
        const float4* xp=(const float4*)(x+(size_t)s*64+q*16);
        float4* xw=(float4*)&xs[e*68+q*16];
        xw[0]=xp[0]; xw[1]=xp[1]; xw[2]=xp[2]; xw[3]=xp[3];
        const int se3=(e&7)<<3;
        if(q==0){
            float4 f0=*(const float4*)(ef+(size_t)ge*8);
            float4 f1=*(const float4*)(ef+(size_t)ge*8+4);
            uint4 o; o.x=pk(f0.x,f0.y); o.y=pk(f0.z,f0.w); o.z=pk(f1.x,f1.y); o.w=pk(f1.z,f1.w);
            *(uint4*)&hA[e*64 + (0^se3)]=o;
            float acc=f0.x*wdens[0]+f0.y*wdens[1]+f0.z*wdens[2]+f0.w*wdens[3]
                     +f1.x*wdens[4]+f1.y*wdens[5]+f1.z*wdens[6]+f1.w*wdens[7];
            acc*=0.35355339059327373f;           // 1/sqrt(8)
            float q2=acc*acc;
            float ex=__expf(2.f*q2);
            ed[ge]=1.f-2.f/(ex+1.f);             // tanh(q2)
        } else if(q==1){
            float4 f0=*(const float4*)(mminv+(size_t)s*8);
            float4 f1=*(const float4*)(mminv+(size_t)s*8+4);
            uint4 o; o.x=pk(f0.x,f0.y); o.y=pk(f0.z,f0.w); o.z=pk(f1.x,f1.y); o.w=pk(f1.z,f1.w);
            *(uint4*)&hA[e*64 + (8^se3)]=o;
        } else if(q==2){
            *(uint4*)&hA[e*64 + (16^se3)]=make_uint4(0,0,0,0);
        } else {
            *(uint4*)&hA[e*64 + (24^se3)]=make_uint4(0,0,0,0);
        }
    }
    __syncthreads();

    const int arow=wv*16+(lane&15);
    const int akg=lane>>4;
    const int aswz=(arow&7)<<3;
    const int dcol=lane&15;
    const int drow0=wv*16+(lane>>4)*4;

    // ---- L1 ----
    {
        uint4 av=*(const uint4*)&hA[arow*64+((akg*8)^aswz)];
        bf16x8 a; __builtin_memcpy(&a,&av,16);
        f32x4 d[4];
        #pragma unroll
        for(int nt=0;nt<4;++nt){
            uint4 bw=w0f[nt*64+lane];
            bf16x8 b; __builtin_memcpy(&b,&bw,16);
            f32x4 z={0.f,0.f,0.f,0.f};
            d[nt]=__builtin_amdgcn_mfma_f32_16x16x32_bf16(a,b,z,0,0,0);
        }
        #pragma unroll
        for(int nt=0;nt<4;++nt){
            #pragma unroll
            for(int r=0;r<4;++r){
                int e2=drow0+r, n=nt*16+dcol;
                hB[e2*64 + (n^((e2&7)<<3))]=f2bf(silu_f(d[nt][r]));
            }
        }
    }
    __syncthreads();

    // ---- L2 ----
    {
        uint4 av0=*(const uint4*)&hB[arow*64+(((0+akg)*8)^aswz)];
        uint4 av1=*(const uint4*)&hB[arow*64+(((4+akg)*8)^aswz)];
        bf16x8 a0,a1; __builtin_memcpy(&a0,&av0,16); __builtin_memcpy(&a1,&av1,16);
        f32x4 d[4];
        #pragma unroll
        for(int nt=0;nt<4;++nt){
            uint4 bw0=w1f[(nt*2+0)*64+lane];
            uint4 bw1=w1f[(nt*2+1)*64+lane];
            bf16x8 b0,b1; __builtin_memcpy(&b0,&bw0,16); __builtin_memcpy(&b1,&bw1,16);
            f32x4 z={0.f,0.f,0.f,0.f};
            d[nt]=__builtin_amdgcn_mfma_f32_16x16x32_bf16(a0,b0,z,0,0,0);
            d[nt]=__builtin_amdgcn_mfma_f32_16x16x32_bf16(a1,b1,d[nt],0,0,0);
        }
        #pragma unroll
        for(int nt=0;nt<4;++nt){
            #pragma unroll
            for(int r=0;r<4;++r){
                int e2=drow0+r, n=nt*16+dcol;
                hA[e2*64 + (n^((e2&7)<<3))]=f2bf(silu_f(d[nt][r]));
            }
        }
    }
    __syncthreads();

    // ---- L3 ----
    {
        uint4 av0=*(const uint4*)&hA[arow*64+(((0+akg)*8)^aswz)];
        uint4 av1=*(const uint4*)&hA[arow*64+(((4+akg)*8)^aswz)];
        bf16x8 a0,a1; __builtin_memcpy(&a0,&av0,16); __builtin_memcpy(&a1,&av1,16);
        f32x4 d[4];
        #pragma unroll
        for(int nt=0;nt<4;++nt){
            uint4 bw0=w2f[(nt*2+0)*64+lane];
            uint4 bw1=w2f[(nt*2+1)*64+lane];
            bf16x8 b0,b1; __builtin_memcpy(&b0,&bw0,16); __builtin_memcpy(&b1,&bw1,16);
            f32x4 z={0.f,0.f,0.f,0.f};
            d[nt]=__builtin_amdgcn_mfma_f32_16x16x32_bf16(a0,b0,z,0,0,0);
            d[nt]=__builtin_amdgcn_mfma_f32_16x16x32_bf16(a1,b1,d[nt],0,0,0);
        }
        #pragma unroll
        for(int nt=0;nt<4;++nt){
            #pragma unroll
            for(int r=0;r<4;++r){
                int e2=drow0+r, n=nt*16+dcol;
                hB[e2*64 + (n^((e2&7)<<3))]=f2bf(silu_f(d[nt][r]));
            }
        }
    }
    __syncthreads();

    // ---- phase B ----
    {
        bf16x8 hb[4][2];
        #pragma unroll
        for(int nt2=0;nt2<4;++nt2){
            int erow=nt2*16+(lane&15);
            int esz=(erow&7)<<3;
            #pragma unroll
            for(int ks=0;ks<2;++ks){
                uint4 v=*(const uint4*)&hB[erow*64+(((ks*4+akg)*8)^esz)];
                __builtin_memcpy(&hb[nt2][ks],&v,16);
            }
        }
        const int g=lane>>4;
        const int jo=g>>1, sh=g&1;
        for(int mt=0;mt<8;++mt){
            int mtg=wv*8+mt;
            uint4 aw0=wtf[(mtg*2+0)*64+lane];
            uint4 aw1=wtf[(mtg*2+1)*64+lane];
            bf16x8 a0,a1; __builtin_memcpy(&a0,&aw0,16); __builtin_memcpy(&a1,&aw1,16);
            int j=mtg*2+jo;
            #pragma unroll
            for(int nt2=0;nt2<4;++nt2){
                f32x4 z={0.f,0.f,0.f,0.f};
                f32x4 d=__builtin_amdgcn_mfma_f32_16x16x32_bf16(a0,hb[nt2][0],z,0,0,0);
                d=__builtin_amdgcn_mfma_f32_16x16x32_bf16(a1,hb[nt2][1],d,0,0,0);
                int eloc=nt2*16+(lane&15);
                float xj=xs[eloc*68+j];
                uint2 o; o.x=pk(d[0]*xj,d[1]*xj); o.y=pk(d[2]*xj,d[3]*xj);
                *(uint2*)&wxc[((size_t)(tile+eloc)*64+j)*8+sh*4]=o;
            }
        }
    }
}

// ---------- K3: wave-per-node gather; writes msgd (msg/(1+D)) and mm_raw into d_out
__global__ __launch_bounds__(256) void k_gather(
    const int* __restrict__ rowptr, const int* __restrict__ elist,
    const unsigned short* __restrict__ wxc, const float* __restrict__ ea,
    const float* __restrict__ mattr, const int* __restrict__ sender,
    const float* __restrict__ ed,
    float* __restrict__ out)
{
    const int t=threadIdx.x, wv=t>>6, lane=t&63;
    const int n=blockIdx.x*4+wv;
    const int r0=rowptr[n], r1=rowptr[n+1];
    float msg[16]; float mm[16];
    #pragma unroll
    for(int m=0;m<16;++m){ msg[m]=0.f; mm[m]=0.f; }
    float dens=0.f;
    for(int k=r0;k<r1;++k){
        int e=elist[k];
        uint4 r=*(const uint4*)(wxc+((size_t)e*64+lane)*8);
        int s=sender[e];
        float wx0=bfl(r.x),wx1=bfh(r.x),wx2=bfl(r.y),wx3=bfh(r.y);
        float wm0=bfl(r.z),wm1=bfh(r.z),wm2=bfl(r.w),wm3=bfh(r.w);
        dens+=ed[e];
        const float4* eap=(const float4*)(ea+(size_t)e*16);
        const float4* map=(const float4*)(mattr+(size_t)s*16);
        float4 A0=eap[0],A1=eap[1],A2=eap[2],A3=eap[3];
        float4 B0=map[0],B1=map[1],B2=map[2],B3=map[3];
        msg[0]+=wx0*A0.x;
        msg[1]+=wx1*A0.y;  msg[2]+=wx1*A0.z;  msg[3]+=wx1*A0.w;
        msg[4]+=wx2*A1.x;  msg[5]+=wx2*A1.y;  msg[6]+=wx2*A1.z;  msg[7]+=wx2*A1.w;  msg[8]+=wx2*A2.x;
        msg[9]+=wx3*A2.y;  msg[10]+=wx3*A2.z; msg[11]+=wx3*A2.w;
        msg[12]+=wx3*A3.x; msg[13]+=wx3*A3.y; msg[14]+=wx3*A3.z; msg[15]+=wx3*A3.w;
        mm[0]+=wm0*B0.x;
        mm[1]+=wm1*B0.y;  mm[2]+=wm1*B0.z;  mm[3]+=wm1*B0.w;
        mm[4]+=wm2*B1.x;  mm[5]+=wm2*B1.y;  mm[6]+=wm2*B1.z;  mm[7]+=wm2*B1.w;  mm[8]+=wm2*B2.x;
        mm[9]+=wm3*B2.y;  mm[10]+=wm3*B2.z; mm[11]+=wm3*B2.w;
        mm[12]+=wm3*B3.x; mm[13]+=wm3*B3.y; mm[14]+=wm3*B3.z; mm[15]+=wm3*B3.w;
    }
    float inv=1.f/(1.f+dens);
    float* mp=out+(size_t)n*1024+lane*16;
    ((float4*)mp)[0]=make_float4(msg[0]*inv,msg[1]*inv,msg[2]*inv,msg[3]*inv);
    ((float4*)mp)[1]=make_float4(msg[4]*inv,msg[5]*inv,msg[6]*inv,msg[7]*inv);
    ((float4*)mp)[2]=make_float4(msg[8]*inv,msg[9]*inv,msg[10]*inv,msg[11]*inv);
    ((float4*)mp)[3]=make_float4(msg[12]*inv,msg[13]*inv,msg[14]*inv,msg[15]*inv);
    float* qp=out+8388608+(size_t)n*1024+lane*16;
    ((float4*)qp)[0]=make_float4(mm[0],mm[1],mm[2],mm[3]);
    ((float4*)qp)[1]=make_float4(mm[4],mm[5],mm[6],mm[7]);
    ((float4*)qp)[2]=make_float4(mm[8],mm[9],mm[10],mm[11]);
    ((float4*)qp)[3]=make_float4(mm[12],mm[13],mm[14],mm[15]);
}

// ---------- K4 v13: transposed MFMA + [n][cx][slot] layout + TWO c-PASSES (16KB LDS).
// LDS halved 32->16KB so the full 8 blocks/CU grid is co-resident (TLP ~2x).
// Per pass: stage c-half contiguously (conflict-free), compute 32 c's with the
// R16 register-prefetch pipeline.
#define MSGRD_(fa_,fb_, cc) { \
    const float* rp_=msgBase + (((cc)^nn)<<3); \
    fa_=*(const float4*)(rp_+sel); \
    fb_=*(const float4*)(rp_+(4-sel)); }
#define TCOMP0_(fa_,fb_, v0,v1,v2) { \
    _Pragma("unroll") \
    for(int r_=0;r_<4;++r_){ \
        acc[r_][0]+=fa_.x*v0[r_]; \
        acc[r_][1]+=fa_.y*v1[r_]; \
        acc[r_][2]+=fa_.z*v1[r_]; \
        acc[r_][3]+=fa_.w*v1[r_]; \
        acc[r_][4]+=fb_.x*v2[r_]; \
        acc[r_][5]+=fb_.y*v2[r_]; \
        acc[r_][6]+=fb_.z*v2[r_]; \
        acc[r_][7]+=fb_.w*v2[r_]; \
    } }
#define TCOMP1_(fa_,fb_, v0,v1) { \
    _Pragma("unroll") \
    for(int r_=0;r_<4;++r_){ \
        acc[r_][0]+=fa_.x*v0[r_]; \
        acc[r_][1]+=fa_.y*v1[r_]; \
        acc[r_][2]+=fa_.z*v1[r_]; \
        acc[r_][3]+=fa_.w*v1[r_]; \
        acc[r_][4]+=fb_.x*v1[r_]; \
        acc[r_][5]+=fb_.y*v1[r_]; \
        acc[r_][6]+=fb_.z*v1[r_]; \
        acc[r_][7]+=fb_.w*v1[r_]; \
    } }
#define MFMA1T_(o, b) { \
    bf16x8 f_; __builtin_memcpy(&f_,&(b),16); \
    f32x4 z_={0.f,0.f,0.f,0.f}; \
    o=__builtin_amdgcn_mfma_f32_16x16x32_bf16(f_,afrag,z_,0,0,0); }
#define STAGE_PASS_(pass_) { \
    _Pragma("unroll") \
    for(int i_=0;i_<4;++i_){ \
        int tau_=i_*256+t; \
        int n_=tau_>>6, rem_=tau_&63, c_=rem_>>1, qq_=rem_&1; \
        float4 f_=src[(n_<<8)+(((pass_)*32+c_)<<2)+half*2+qq_]; \
        int idx4_=(n_<<6)+((c_^(n_&15))<<1)+(qq_^((n_>>2)&1)); \
        *(float4*)&msgSf[idx4_<<2]=f_; \
    } }

__global__ __launch_bounds__(256) void k_final13(const float* __restrict__ attrs,
                                                 const unsigned* __restrict__ wwf,
                                                 float* __restrict__ out){
    __shared__ float msgSf[16*32*8];   // [n][cx 32][slot 2][4] f32, 16384 B
    const int blk=blockIdx.x;
    const int half=blk&1;
    const int rest=blk>>1;
    const int ten=rest>>9, nb=(rest&511)*16;
    float* base=out+(size_t)ten*8388608;
    const int t=threadIdx.x, lane=t&63, wg=t>>6;
    const float4* src=(const float4*)(base+(size_t)nb*1024);

    // attrs B-fragment: B[v=(lane>>4)*8+i][n=lane&15] = attrs[nb+n][v]  (zero for v>=16)
    bf16x8 afrag;
    {
        int nloc=lane&15, kg=lane>>4;
        if(kg<2){
            const float* ap=attrs+(size_t)(nb+nloc)*16+kg*8;
            #pragma unroll
            for(int i=0;i<8;++i) afrag[i]=(short)f2bf(ap[i]);
        } else {
            #pragma unroll
            for(int i=0;i<8;++i) afrag[i]=0;
        }
    }

    const int nn=lane&15;              // thread's node (D col)
    const int g4=(lane>>4)*4;          // thread's first w-row (D row base)
    const float* msgBase=&msgSf[nn<<8];   // n*256 floats
    const int sel=((nn>>2)&1)*4;          // slot select, loop-invariant
    float acc[4][8];
    #pragma unroll
    for(int r=0;r<4;++r)
        #pragma unroll
        for(int m=0;m<8;++m) acc[r][m]=0.f;

    const uint4* wwf4=(const uint4*)wwf;
    const int l31=lane&31;

    if(half==0){
        const uint4* q0=wwf4+((size_t)((ten*4+0)*64)*4+wg)*32+l31;
        const uint4* q1=wwf4+((size_t)((ten*4+1)*64)*4+wg)*32+l31;
        const uint4* q2=wwf4+((size_t)((ten*4+2)*64)*4+wg)*32+l31;
        #pragma unroll
        for(int pass=0;pass<2;++pass){
            STAGE_PASS_(pass);
            __syncthreads();
            const uint4* p0=q0+pass*4096;
            const uint4* p1=q1+pass*4096;
            const uint4* p2=q2+pass*4096;
            uint4 A0=p0[0], A1=p1[0], A2=p2[0];
            uint4 B0=p0[128], B1=p1[128], B2=p2[128];
            f32x4 dA0,dA1,dA2, dB0,dB1,dB2;
            float4 mfa,mfb, nfa,nfb;
            MFMA1T_(dA0,A0); MFMA1T_(dA1,A1); MFMA1T_(dA2,A2);
            MSGRD_(mfa,mfb, 0);
            for(int c=0;c<32;c+=2){
                const int cA=(c+2<32)? c+2 : 31;
                const int cB=(c+3<32)? c+3 : 31;
                MSGRD_(nfa,nfb, c+1);                              // prefetch msg(c+1)
                A0=p0[cA*128]; A1=p1[cA*128]; A2=p2[cA*128];
                MFMA1T_(dB0,B0); MFMA1T_(dB1,B1); MFMA1T_(dB2,B2); // Wn(c+1)
                TCOMP0_(mfa,mfb, dA0,dA1,dA2);                     // consume msg(c),Wn(c)
                MSGRD_(mfa,mfb, cA);                               // prefetch msg(c+2)
                B0=p0[cB*128]; B1=p1[cB*128]; B2=p2[cB*128];
                MFMA1T_(dA0,A0); MFMA1T_(dA1,A1); MFMA1T_(dA2,A2); // Wn(c+2)
                TCOMP0_(nfa,nfb, dB0,dB1,dB2);                     // consume msg(c+1),Wn(c+1)
            }
            __syncthreads();
        }
    } else {
        const uint4* q0=wwf4+((size_t)((ten*4+2)*64)*4+wg)*32+l31;
        const uint4* q1=wwf4+((size_t)((ten*4+3)*64)*4+wg)*32+l31;
        #pragma unroll
        for(int pass=0;pass<2;++pass){
            STAGE_PASS_(pass);
            __syncthreads();
            const uint4* p0=q0+pass*4096;
            const uint4* p1=q1+pass*4096;
            uint4 A0=p0[0], A1=p1[0];
            uint4 B0=p0[128], B1=p1[128];
            f32x4 dA0,dA1, dB0,dB1;
            float4 mfa,mfb, nfa,nfb;
            MFMA1T_(dA0,A0); MFMA1T_(dA1,A1);
            MSGRD_(mfa,mfb, 0);
            for(int c=0;c<32;c+=2){
                const int cA=(c+2<32)? c+2 : 31;
                const int cB=(c+3<32)? c+3 : 31;
                MSGRD_(nfa,nfb, c+1);
                A0=p0[cA*128]; A1=p1[cA*128];
                MFMA1T_(dB0,B0); MFMA1T_(dB1,B1);
                TCOMP1_(mfa,mfb, dA0,dA1);
                MSGRD_(mfa,mfb, cA);
                B0=p0[cB*128]; B1=p1[cB*128];
                MFMA1T_(dA0,A0); MFMA1T_(dA1,A1);
                TCOMP1_(nfa,nfb, dB0,dB1);
            }
            __syncthreads();
        }
    }

    // epilogue: thread writes out[nb+nn][w=wg*16+g4+r][m=half*8 .. +7]
    #pragma unroll
    for(int r=0;r<4;++r){
        float* op=base+(size_t)(nb+nn)*1024+(wg*16+g4+r)*16+half*8;
        ((float4*)op)[0]=make_float4(acc[r][0],acc[r][1],acc[r][2],acc[r][3]);
        ((float4*)op)[1]=make_float4(acc[r][4],acc[r][5],acc[r][6],acc[r][7]);
    }
}

extern "C" void kernel_launch(void* const* d_in, const int* in_sizes, int n_in,
                              void* d_out, int out_size, void* d_ws, size_t ws_size,
                              hipStream_t stream) {
    const float* node_attrs=(const float*)d_in[0];
    const float* node_feats=(const float*)d_in[1];
    const float* edge_attrs=(const float*)d_in[2];
    const float* edge_feats=(const float*)d_in[3];
    const int*   eidx_in  =(const int*)  d_in[4];
    const int*   sender   =eidx_in;
    const int*   recv     =eidx_in+N_EDGES;
    const float* mminv    =(const float*)d_in[5];
    const float* mattr    =(const float*)d_in[6];
    const float* wup      =(const float*)d_in[7];
    const float* wr0      =(const float*)d_in[8];
    const float* wr1      =(const float*)d_in[9];
    const float* wr2      =(const float*)d_in[10];
    const float* wr3      =(const float*)d_in[11];
    const float* wtr      =(const float*)d_in[12];
    const float* wdens    =(const float*)d_in[13];
    const float* wlin     =(const float*)d_in[14];
    const float* wmlin    =(const float*)d_in[15];
    const float* wskip    =(const float*)d_in[16];
    const float* wmskip   =(const float*)d_in[17];

    char* ws=(char*)d_ws;
    float*          x     =(float*)(ws+0);                      //  2 MB
    unsigned short* wxc   =(unsigned short*)(ws+2097152);       // 64 MB ([e][j][8] bf16)
    float*          ed    =(float*)(ws+73400320);               // 256 KB
    unsigned short* wtf   =(unsigned short*)(ws+73662464);      // 64 KB
    unsigned*       wwf   =(unsigned*)(ws+73728000);            //  2 MB
    unsigned short* w0f   =(unsigned short*)(ws+75825152);      //  4 KB
    unsigned short* w1f   =(unsigned short*)(ws+75829248);      //  8 KB
    unsigned short* w2f   =(unsigned short*)(ws+75837440);      //  8 KB
    int*            cnt   =(int*)(ws+75845632);                 // 32 KB
    int*            rowptr=(int*)(ws+75878400);                 // 32 KB + 4 (pad to 75911296)
    int*            cur   =(int*)(ws+75911296);                 // 32 KB
    int*            elist =(int*)(ws+75944064);                 // 256 KB -> 76206208
    if(ws_size < (size_t)76206208) return;   // insufficient scratch: fail loudly

    float* out=(float*)d_out;

    hipMemsetAsync(cnt,0,32768,stream);
    k_prep   <<<dim3(2900),dim3(256),0,stream>>>(node_feats,wup,x,
                                                 wr0,wr1,wr2,w0f,w1f,w2f,
                                                 wr3,wtr,wtf,
                                                 wlin,wmlin,wskip,wmskip,wwf,
                                                 recv,cnt);
    k_scan   <<<dim3(1),   dim3(1024),0,stream>>>(cnt,rowptr,cur);
    k_mid    <<<dim3(1280),dim3(256),0,stream>>>(recv,cur,elist,
                                                 edge_feats,mminv,sender,wdens,
                                                 (const uint4*)w0f,(const uint4*)w1f,
                                                 (const uint4*)w2f,(const uint4*)wtf,
                                                 x,wxc,ed);
    k_gather <<<dim3(2048),dim3(256),0,stream>>>(rowptr,elist,wxc,edge_attrs,mattr,sender,ed,out);
    k_final13<<<dim3(2048),dim3(256),0,stream>>>(node_attrs,wwf,out);
}

// Round 20
// 213.509 us; speedup vs baseline: 1.0082x; 1.0082x over previous
//
#include <hip/hip_runtime.h>

// Problem constants
#define N_NODES 8192
#define N_EDGES 65536

typedef __attribute__((ext_vector_type(8))) short bf16x8;
typedef __attribute__((ext_vector_type(4))) float f32x4;

// ---------- bf16 helpers (OCP bf16 = top 16 bits of f32, RNE) ----------
static __device__ __forceinline__ float bfl(unsigned v){ unsigned u=v<<16; float f; __builtin_memcpy(&f,&u,4); return f; }
static __device__ __forceinline__ float bfh(unsigned v){ unsigned u=v&0xffff0000u; float f; __builtin_memcpy(&f,&u,4); return f; }
static __device__ __forceinline__ unsigned short f2bf(float f){ unsigned u; __builtin_memcpy(&u,&f,4); u += 0x7fffu + ((u>>16)&1u); return (unsigned short)(u>>16); }
static __device__ __forceinline__ unsigned pk(float a, float b){ return (unsigned)f2bf(a) | ((unsigned)f2bf(b)<<16); }
static __device__ __forceinline__ float silu_f(float v){ return v/(1.f+__expf(-v)); }

// ---------- K_prep: fused {linup | wmlp | wtf(serial) | wwf | count} by block range ----------
__global__ __launch_bounds__(256) void k_prep(
    const float* __restrict__ nf,  const float* __restrict__ wup,  float* __restrict__ x,
    const float* __restrict__ wr0, const float* __restrict__ wr1,  const float* __restrict__ wr2,
    unsigned short* __restrict__ w0f, unsigned short* __restrict__ w1f, unsigned short* __restrict__ w2f,
    const float* __restrict__ wr3, const float* __restrict__ wtr,  unsigned short* __restrict__ wtf,
    const float* __restrict__ wlin, const float* __restrict__ wmlin,
    const float* __restrict__ wskip, const float* __restrict__ wmskip, unsigned* __restrict__ wwf,
    const int* __restrict__ recv, int* __restrict__ cnt)
{
    const int bid=blockIdx.x, t=threadIdx.x;
    if(bid<2048){
        __shared__ float s[4][64];
        const int wv=t>>6, lane=t&63;
        const int n=bid*4+wv;
        s[wv][lane]=nf[(size_t)n*64+lane];
        __syncthreads();
        float acc=0.f;
        for(int c=0;c<64;++c) acc += s[wv][c]*wup[c*64+lane];
        x[(size_t)n*64+lane]=acc*0.125f;
    } else if(bid<2068){
        const int b=bid-2048;
        #pragma unroll
        for(int z=0;z<2;++z){
            int idx=t*2+z;
            int lane=idx>>3, i=idx&7;
            if(b<4){
                int nt=b, k=(lane>>4)*8+i, n=nt*16+(lane&15);
                float v=(k<16)? wr0[k*64+n]*0.25f : 0.f;
                w0f[(nt*64+lane)*8+i]=f2bf(v);
            } else if(b<12){
                int q=b-4, nt=q>>1, ks=q&1;
                int k=ks*32+(lane>>4)*8+i, n=nt*16+(lane&15);
                w1f[((nt*2+ks)*64+lane)*8+i]=f2bf(wr1[k*64+n]*0.125f);
            } else {
                int q=b-12, nt=q>>1, ks=q&1;
                int k=ks*32+(lane>>4)*8+i, n=nt*16+(lane&15);
                w2f[((nt*2+ks)*64+lane)*8+i]=f2bf(wr2[k*64+n]*0.125f);
            }
        }
    } else if(bid<2132){
        const int b=bid-2068;          // 0..63 = mt*2+ks
        const int mt=b>>1, ks=b&1;
        #pragma unroll
        for(int z=0;z<2;++z){
            int idx=t*2+z;
            int lane=idx>>3, i=idx&7;
            int k=ks*32+(lane>>4)*8+i;
            int n=mt*16+(lane&15);
            int j=n>>3, s=n&7;
            float v;
            if(s<4) v=wr3[k*256+s*64+j]*0.125f;
            else {
                float acc=0.f;
                for(int kk=0;kk<256;++kk) acc+=wr3[k*256+kk]*wtr[kk*256+(s-4)*64+j];
                v=acc*(1.f/128.f);
            }
            wtf[((size_t)b*64+lane)*8+i]=f2bf(v);
        }
    } else if(bid<2644){
        const int b=bid-2132, ten=b>>8, lc=b&255, l=lc>>6, c=lc&63;
        const float* WL = ten? wmlin:wlin;
        const float* WS = ten? wmskip:wskip;
        const float scale = ten? (1.f/4096.f):(1.f/256.f);
        const int wg=t>>6, s=t&63, lane=s>>1, half=s&1;
        const int w=wg*16+(lane&15);
        const int v0=(lane>>4)*8+half*4;
        float a0=0,a1=0,a2=0,a3=0;
        for(int u=0;u<64;++u){
            float wl=WL[(l*64+c)*64+u];
            const float* wsp=&WS[(((l*64+u)*16+v0)*64)+w];
            a0+=wl*wsp[0]; a1+=wl*wsp[64]; a2+=wl*wsp[128]; a3+=wl*wsp[192];
        }
        size_t fi=(((size_t)ten*4+l)*64+c)*4+wg;
        unsigned* op=wwf + (fi*32+lane)*4 + half*2;
        op[0]=pk(a0*scale,a1*scale); op[1]=pk(a2*scale,a3*scale);
    } else {
        int e=(bid-2644)*256+t;
        atomicAdd(&cnt[recv[e]],1);
    }
}

// ---------- k_scan ----------
__global__ __launch_bounds__(1024) void k_scan(const int* __restrict__ cnt, int* __restrict__ rowptr, int* __restrict__ cur){
    __shared__ int s[1024];
    const int t=threadIdx.x;
    int c[8]; int sum=0;
    #pragma unroll
    for(int i=0;i<8;++i){ c[i]=cnt[t*8+i]; sum+=c[i]; }
    s[t]=sum; __syncthreads();
    for(int off=1;off<1024;off<<=1){
        int v=s[t]; int add=(t>=off)? s[t-off]:0;
        __syncthreads();
        s[t]=v+add;
        __syncthreads();
    }
    int run=s[t]-sum;
    #pragma unroll
    for(int i=0;i<8;++i){ rowptr[t*8+i]=run; cur[t*8+i]=run; run+=c[i]; }
    if(t==1023) rowptr[8192]=run;
}

// ---------- K_mid: fused {scatter | edge2} by block range ----------
__global__ __launch_bounds__(256) void k_mid(
    const int* __restrict__ recv, int* __restrict__ cur, int* __restrict__ elist,
    const float* __restrict__ ef, const float* __restrict__ mminv,
    const int* __restrict__ sender,
    const float* __restrict__ wdens,
    const uint4* __restrict__ w0f, const uint4* __restrict__ w1f,
    const uint4* __restrict__ w2f, const uint4* __restrict__ wtf,
    const float* __restrict__ x,
    unsigned short* __restrict__ wxc, float* __restrict__ ed)
{
    __shared__ unsigned short hA[4096];   // 8KB  [e][k] bf16 swizzled
    __shared__ unsigned short hB[4096];   // 8KB
    __shared__ float xs[64*68];           // 17KB [e][j pad 68]
    const int bid=blockIdx.x, t=threadIdx.x;
    if(bid<256){
        int e=bid*256+t;
        int r=recv[e];
        int p=atomicAdd(&cur[r],1);
        elist[p]=e;
        return;
    }
    const int lane=t&63, wv=t>>6;
    const int tile=(bid-256)*64;

    {
        const int e=t>>2, q=t&3, ge=tile+e;
        const int s=sender[ge];
        const float4* xp=(const float4*)(x+(size_t)s*64+q*16);
        float4* xw=(float4*)&xs[e*68+q*16];
        xw[0]=xp[0]; xw[1]=xp[1]; xw[2]=xp[2]; xw[3]=xp[3];
        const int se3=(e&7)<<3;
        if(q==0){
            float4 f0=*(const float4*)(ef+(size_t)ge*8);
            float4 f1=*(const float4*)(ef+(size_t)ge*8+4);
            uint4 o; o.x=pk(f0.x,f0.y); o.y=pk(f0.z,f0.w); o.z=pk(f1.x,f1.y); o.w=pk(f1.z,f1.w);
            *(uint4*)&hA[e*64 + (0^se3)]=o;
            float acc=f0.x*wdens[0]+f0.y*wdens[1]+f0.z*wdens[2]+f0.w*wdens[3]
                     +f1.x*wdens[4]+f1.y*wdens[5]+f1.z*wdens[6]+f1.w*wdens[7];
            acc*=0.35355339059327373f;           // 1/sqrt(8)
            float q2=acc*acc;
            float ex=__expf(2.f*q2);
            ed[ge]=1.f-2.f/(ex+1.f);             // tanh(q2)
        } else if(q==1){
            float4 f0=*(const float4*)(mminv+(size_t)s*8);
            float4 f1=*(const float4*)(mminv+(size_t)s*8+4);
            uint4 o; o.x=pk(f0.x,f0.y); o.y=pk(f0.z,f0.w); o.z=pk(f1.x,f1.y); o.w=pk(f1.z,f1.w);
            *(uint4*)&hA[e*64 + (8^se3)]=o;
        } else if(q==2){
            *(uint4*)&hA[e*64 + (16^se3)]=make_uint4(0,0,0,0);
        } else {
            *(uint4*)&hA[e*64 + (24^se3)]=make_uint4(0,0,0,0);
        }
    }
    __syncthreads();

    const int arow=wv*16+(lane&15);
    const int akg=lane>>4;
    const int aswz=(arow&7)<<3;
    const int dcol=lane&15;
    const int drow0=wv*16+(lane>>4)*4;

    // ---- L1 ----
    {
        uint4 av=*(const uint4*)&hA[arow*64+((akg*8)^aswz)];
        bf16x8 a; __builtin_memcpy(&a,&av,16);
        f32x4 d[4];
        #pragma unroll
        for(int nt=0;nt<4;++nt){
            uint4 bw=w0f[nt*64+lane];
            bf16x8 b; __builtin_memcpy(&b,&bw,16);
            f32x4 z={0.f,0.f,0.f,0.f};
            d[nt]=__builtin_amdgcn_mfma_f32_16x16x32_bf16(a,b,z,0,0,0);
        }
        #pragma unroll
        for(int nt=0;nt<4;++nt){
            #pragma unroll
            for(int r=0;r<4;++r){
                int e2=drow0+r, n=nt*16+dcol;
                hB[e2*64 + (n^((e2&7)<<3))]=f2bf(silu_f(d[nt][r]));
            }
        }
    }
    __syncthreads();

    // ---- L2 ----
    {
        uint4 av0=*(const uint4*)&hB[arow*64+(((0+akg)*8)^aswz)];
        uint4 av1=*(const uint4*)&hB[arow*64+(((4+akg)*8)^aswz)];
        bf16x8 a0,a1; __builtin_memcpy(&a0,&av0,16); __builtin_memcpy(&a1,&av1,16);
        f32x4 d[4];
        #pragma unroll
        for(int nt=0;nt<4;++nt){
            uint4 bw0=w1f[(nt*2+0)*64+lane];
            uint4 bw1=w1f[(nt*2+1)*64+lane];
            bf16x8 b0,b1; __builtin_memcpy(&b0,&bw0,16); __builtin_memcpy(&b1,&bw1,16);
            f32x4 z={0.f,0.f,0.f,0.f};
            d[nt]=__builtin_amdgcn_mfma_f32_16x16x32_bf16(a0,b0,z,0,0,0);
            d[nt]=__builtin_amdgcn_mfma_f32_16x16x32_bf16(a1,b1,d[nt],0,0,0);
        }
        #pragma unroll
        for(int nt=0;nt<4;++nt){
            #pragma unroll
            for(int r=0;r<4;++r){
                int e2=drow0+r, n=nt*16+dcol;
                hA[e2*64 + (n^((e2&7)<<3))]=f2bf(silu_f(d[nt][r]));
            }
        }
    }
    __syncthreads();

    // ---- L3 ----
    {
        uint4 av0=*(const uint4*)&hA[arow*64+(((0+akg)*8)^aswz)];
        uint4 av1=*(const uint4*)&hA[arow*64+(((4+akg)*8)^aswz)];
        bf16x8 a0,a1; __builtin_memcpy(&a0,&av0,16); __builtin_memcpy(&a1,&av1,16);
        f32x4 d[4];
        #pragma unroll
        for(int nt=0;nt<4;++nt){
            uint4 bw0=w2f[(nt*2+0)*64+lane];
            uint4 bw1=w2f[(nt*2+1)*64+lane];
            bf16x8 b0,b1; __builtin_memcpy(&b0,&bw0,16); __builtin_memcpy(&b1,&bw1,16);
            f32x4 z={0.f,0.f,0.f,0.f};
            d[nt]=__builtin_amdgcn_mfma_f32_16x16x32_bf16(a0,b0,z,0,0,0);
            d[nt]=__builtin_amdgcn_mfma_f32_16x16x32_bf16(a1,b1,d[nt],0,0,0);
        }
        #pragma unroll
        for(int nt=0;nt<4;++nt){
            #pragma unroll
            for(int r=0;r<4;++r){
                int e2=drow0+r, n=nt*16+dcol;
                hB[e2*64 + (n^((e2&7)<<3))]=f2bf(silu_f(d[nt][r]));
            }
        }
    }
    __syncthreads();

    // ---- phase B ----
    {
        bf16x8 hb[4][2];
        #pragma unroll
        for(int nt2=0;nt2<4;++nt2){
            int erow=nt2*16+(lane&15);
            int esz=(erow&7)<<3;
            #pragma unroll
            for(int ks=0;ks<2;++ks){
                uint4 v=*(const uint4*)&hB[erow*64+(((ks*4+akg)*8)^esz)];
                __builtin_memcpy(&hb[nt2][ks],&v,16);
            }
        }
        const int g=lane>>4;
        const int jo=g>>1, sh=g&1;
        for(int mt=0;mt<8;++mt){
            int mtg=wv*8+mt;
            uint4 aw0=wtf[(mtg*2+0)*64+lane];
            uint4 aw1=wtf[(mtg*2+1)*64+lane];
            bf16x8 a0,a1; __builtin_memcpy(&a0,&aw0,16); __builtin_memcpy(&a1,&aw1,16);
            int j=mtg*2+jo;
            #pragma unroll
            for(int nt2=0;nt2<4;++nt2){
                f32x4 z={0.f,0.f,0.f,0.f};
                f32x4 d=__builtin_amdgcn_mfma_f32_16x16x32_bf16(a0,hb[nt2][0],z,0,0,0);
                d=__builtin_amdgcn_mfma_f32_16x16x32_bf16(a1,hb[nt2][1],d,0,0,0);
                int eloc=nt2*16+(lane&15);
                float xj=xs[eloc*68+j];
                uint2 o; o.x=pk(d[0]*xj,d[1]*xj); o.y=pk(d[2]*xj,d[3]*xj);
                *(uint2*)&wxc[((size_t)(tile+eloc)*64+j)*8+sh*4]=o;
            }
        }
    }
}

// ---------- K3: wave-per-node gather; writes msgd (msg/(1+D)) and mm_raw into d_out
__global__ __launch_bounds__(256) void k_gather(
    const int* __restrict__ rowptr, const int* __restrict__ elist,
    const unsigned short* __restrict__ wxc, const float* __restrict__ ea,
    const float* __restrict__ mattr, const int* __restrict__ sender,
    const float* __restrict__ ed,
    float* __restrict__ out)
{
    const int t=threadIdx.x, wv=t>>6, lane=t&63;
    const int n=blockIdx.x*4+wv;
    const int r0=rowptr[n], r1=rowptr[n+1];
    float msg[16]; float mm[16];
    #pragma unroll
    for(int m=0;m<16;++m){ msg[m]=0.f; mm[m]=0.f; }
    float dens=0.f;
    for(int k=r0;k<r1;++k){
        int e=elist[k];
        uint4 r=*(const uint4*)(wxc+((size_t)e*64+lane)*8);
        int s=sender[e];
        float wx0=bfl(r.x),wx1=bfh(r.x),wx2=bfl(r.y),wx3=bfh(r.y);
        float wm0=bfl(r.z),wm1=bfh(r.z),wm2=bfl(r.w),wm3=bfh(r.w);
        dens+=ed[e];
        const float4* eap=(const float4*)(ea+(size_t)e*16);
        const float4* map=(const float4*)(mattr+(size_t)s*16);
        float4 A0=eap[0],A1=eap[1],A2=eap[2],A3=eap[3];
        float4 B0=map[0],B1=map[1],B2=map[2],B3=map[3];
        msg[0]+=wx0*A0.x;
        msg[1]+=wx1*A0.y;  msg[2]+=wx1*A0.z;  msg[3]+=wx1*A0.w;
        msg[4]+=wx2*A1.x;  msg[5]+=wx2*A1.y;  msg[6]+=wx2*A1.z;  msg[7]+=wx2*A1.w;  msg[8]+=wx2*A2.x;
        msg[9]+=wx3*A2.y;  msg[10]+=wx3*A2.z; msg[11]+=wx3*A2.w;
        msg[12]+=wx3*A3.x; msg[13]+=wx3*A3.y; msg[14]+=wx3*A3.z; msg[15]+=wx3*A3.w;
        mm[0]+=wm0*B0.x;
        mm[1]+=wm1*B0.y;  mm[2]+=wm1*B0.z;  mm[3]+=wm1*B0.w;
        mm[4]+=wm2*B1.x;  mm[5]+=wm2*B1.y;  mm[6]+=wm2*B1.z;  mm[7]+=wm2*B1.w;  mm[8]+=wm2*B2.x;
        mm[9]+=wm3*B2.y;  mm[10]+=wm3*B2.z; mm[11]+=wm3*B2.w;
        mm[12]+=wm3*B3.x; mm[13]+=wm3*B3.y; mm[14]+=wm3*B3.z; mm[15]+=wm3*B3.w;
    }
    float inv=1.f/(1.f+dens);
    float* mp=out+(size_t)n*1024+lane*16;
    ((float4*)mp)[0]=make_float4(msg[0]*inv,msg[1]*inv,msg[2]*inv,msg[3]*inv);
    ((float4*)mp)[1]=make_float4(msg[4]*inv,msg[5]*inv,msg[6]*inv,msg[7]*inv);
    ((float4*)mp)[2]=make_float4(msg[8]*inv,msg[9]*inv,msg[10]*inv,msg[11]*inv);
    ((float4*)mp)[3]=make_float4(msg[12]*inv,msg[13]*inv,msg[14]*inv,msg[15]*inv);
    float* qp=out+8388608+(size_t)n*1024+lane*16;
    ((float4*)qp)[0]=make_float4(mm[0],mm[1],mm[2],mm[3]);
    ((float4*)qp)[1]=make_float4(mm[4],mm[5],mm[6],mm[7]);
    ((float4*)qp)[2]=make_float4(mm[8],mm[9],mm[10],mm[11]);
    ((float4*)qp)[3]=make_float4(mm[12],mm[13],mm[14],mm[15]);
}

// ---------- K4 v14: R16 transposed-MFMA kernel + 4-step fragment pipeline.
// Fragments for c+4..c+7 are loaded 1.5-2 iterations before their MFMA (covers L2 latency).
// msg reads remain direct (R16-style; R17 showed prefetching them is net-negative).
#define TSTEP0_(v0,v1,v2, cc) { \
    const float* rp_=&msgSf[(((cc)*16+nn))*8]; \
    float4 fa_=*(const float4*)(rp_+swsel); \
    float4 fb_=*(const float4*)(rp_+(4-swsel)); \
    _Pragma("unroll") \
    for(int r_=0;r_<4;++r_){ \
        acc[r_][0]+=fa_.x*v0[r_]; \
        acc[r_][1]+=fa_.y*v1[r_]; \
        acc[r_][2]+=fa_.z*v1[r_]; \
        acc[r_][3]+=fa_.w*v1[r_]; \
        acc[r_][4]+=fb_.x*v2[r_]; \
        acc[r_][5]+=fb_.y*v2[r_]; \
        acc[r_][6]+=fb_.z*v2[r_]; \
        acc[r_][7]+=fb_.w*v2[r_]; \
    } }
#define TSTEP1_(v0,v1, cc) { \
    const float* rp_=&msgSf[(((cc)*16+nn))*8]; \
    float4 fa_=*(const float4*)(rp_+swsel); \
    float4 fb_=*(const float4*)(rp_+(4-swsel)); \
    _Pragma("unroll") \
    for(int r_=0;r_<4;++r_){ \
        acc[r_][0]+=fa_.x*v0[r_]; \
        acc[r_][1]+=fa_.y*v1[r_]; \
        acc[r_][2]+=fa_.z*v1[r_]; \
        acc[r_][3]+=fa_.w*v1[r_]; \
        acc[r_][4]+=fb_.x*v1[r_]; \
        acc[r_][5]+=fb_.y*v1[r_]; \
        acc[r_][6]+=fb_.z*v1[r_]; \
        acc[r_][7]+=fb_.w*v1[r_]; \
    } }
#define MFMA1T_(o, b) { \
    bf16x8 f_; __builtin_memcpy(&f_,&(b),16); \
    f32x4 z_={0.f,0.f,0.f,0.f}; \
    o=__builtin_amdgcn_mfma_f32_16x16x32_bf16(f_,afrag,z_,0,0,0); }

__global__ __launch_bounds__(256) void k_final14(const float* __restrict__ attrs,
                                                 const unsigned* __restrict__ wwf,
                                                 float* __restrict__ out){
    __shared__ float msgSf[64*16*8];   // [c][n][8m] f32, 32768 B (half-swap swizzled)
    const int blk=blockIdx.x;
    const int half=blk&1;
    const int rest=blk>>1;
    const int ten=rest>>9, nb=(rest&511)*16;
    float* base=out+(size_t)ten*8388608;
    const int t=threadIdx.x, lane=t&63, wg=t>>6;

    // stage msg half-slab (f32 [n][c][m]) -> msgSf [c][n][8] (f32, swizzled halves)
    const float4* src=(const float4*)(base+(size_t)nb*1024);
    #pragma unroll
    for(int i=0;i<8;++i){
        int tau=i*256+t;
        int n=tau>>7, rem=tau&127, c=rem>>1, qq=rem&1;
        float4 f=src[(n<<8)+(c<<2)+half*2+qq];
        int slot=qq^((n>>2)&1);
        *(float4*)&msgSf[(c*16+n)*8+slot*4]=f;
    }
    // attrs B-fragment: B[v=(lane>>4)*8+i][n=lane&15] = attrs[nb+n][v]  (zero for v>=16)
    bf16x8 afrag;
    {
        int nloc=lane&15, kg=lane>>4;
        if(kg<2){
            const float* ap=attrs+(size_t)(nb+nloc)*16+kg*8;
            #pragma unroll
            for(int i=0;i<8;++i) afrag[i]=(short)f2bf(ap[i]);
        } else {
            #pragma unroll
            for(int i=0;i<8;++i) afrag[i]=0;
        }
    }
    __syncthreads();

    const int nn=lane&15;              // thread's node (D col)
    const int g4=(lane>>4)*4;          // thread's first w-row (D row base)
    const int swsel=((nn>>2)&1)*4;     // msg half-swap select (floats)
    float acc[4][8];
    #pragma unroll
    for(int r=0;r<4;++r)
        #pragma unroll
        for(int m=0;m<8;++m) acc[r][m]=0.f;

    const uint4* wwf4=(const uint4*)wwf;
    const int l31=lane&31;

    if(half==0){
        const uint4* p0=wwf4+((size_t)((ten*4+0)*64)*4+wg)*32+l31;
        const uint4* p1=wwf4+((size_t)((ten*4+1)*64)*4+wg)*32+l31;
        const uint4* p2=wwf4+((size_t)((ten*4+2)*64)*4+wg)*32+l31;
        uint4 Af0=p0[0],   Af1=p1[0],   Af2=p2[0];
        uint4 Bf0=p0[128], Bf1=p1[128], Bf2=p2[128];
        uint4 Ag0=p0[256], Ag1=p1[256], Ag2=p2[256];
        uint4 Bg0=p0[384], Bg1=p1[384], Bg2=p2[384];
        f32x4 dA0,dA1,dA2v, dB0,dB1,dB2v, dC0,dC1,dC2v, dD0,dD1,dD2v;
        MFMA1T_(dA0,Af0); MFMA1T_(dA1,Af1); MFMA1T_(dA2v,Af2);      // Wn(0)
        for(int c=0;c<64;c+=4){
            const int c4=(c+4<64)?c+4:63, c5=(c+5<64)?c+5:63;
            const int c6=(c+6<64)?c+6:63, c7=(c+7<64)?c+7:63;
            MFMA1T_(dB0,Bf0); MFMA1T_(dB1,Bf1); MFMA1T_(dB2v,Bf2);  // Wn(c+1)
            Af0=p0[c4*128]; Af1=p1[c4*128]; Af2=p2[c4*128];         // frag(c+4)
            Bf0=p0[c5*128]; Bf1=p1[c5*128]; Bf2=p2[c5*128];         // frag(c+5)
            TSTEP0_(dA0,dA1,dA2v, c);
            MFMA1T_(dC0,Ag0); MFMA1T_(dC1,Ag1); MFMA1T_(dC2v,Ag2);  // Wn(c+2)
            TSTEP0_(dB0,dB1,dB2v, c+1);
            MFMA1T_(dD0,Bg0); MFMA1T_(dD1,Bg1); MFMA1T_(dD2v,Bg2);  // Wn(c+3)
            Ag0=p0[c6*128]; Ag1=p1[c6*128]; Ag2=p2[c6*128];         // frag(c+6)
            Bg0=p0[c7*128]; Bg1=p1[c7*128]; Bg2=p2[c7*128];         // frag(c+7)
            TSTEP0_(dC0,dC1,dC2v, c+2);
            MFMA1T_(dA0,Af0); MFMA1T_(dA1,Af1); MFMA1T_(dA2v,Af2);  // Wn(c+4)
            TSTEP0_(dD0,dD1,dD2v, c+3);
        }
    } else {
        const uint4* p0=wwf4+((size_t)((ten*4+2)*64)*4+wg)*32+l31;
        const uint4* p1=wwf4+((size_t)((ten*4+3)*64)*4+wg)*32+l31;
        uint4 Af0=p0[0],   Af1=p1[0];
        uint4 Bf0=p0[128], Bf1=p1[128];
        uint4 Ag0=p0[256], Ag1=p1[256];
        uint4 Bg0=p0[384], Bg1=p1[384];
        f32x4 dA0,dA1, dB0,dB1, dC0,dC1, dD0,dD1;
        MFMA1T_(dA0,Af0); MFMA1T_(dA1,Af1);                         // Wn(0)
        for(int c=0;c<64;c+=4){
            const int c4=(c+4<64)?c+4:63, c5=(c+5<64)?c+5:63;
            const int c6=(c+6<64)?c+6:63, c7=(c+7<64)?c+7:63;
            MFMA1T_(dB0,Bf0); MFMA1T_(dB1,Bf1);                     // Wn(c+1)
            Af0=p0[c4*128]; Af1=p1[c4*128];
            Bf0=p0[c5*128]; Bf1=p1[c5*128];
            TSTEP1_(dA0,dA1, c);
            MFMA1T_(dC0,Ag0); MFMA1T_(dC1,Ag1);                     // Wn(c+2)
            TSTEP1_(dB0,dB1, c+1);
            MFMA1T_(dD0,Bg0); MFMA1T_(dD1,Bg1);                     // Wn(c+3)
            Ag0=p0[c6*128]; Ag1=p1[c6*128];
            Bg0=p0[c7*128]; Bg1=p1[c7*128];
            TSTEP1_(dC0,dC1, c+2);
            MFMA1T_(dA0,Af0); MFMA1T_(dA1,Af1);                     // Wn(c+4)
            TSTEP1_(dD0,dD1, c+3);
        }
    }

    // epilogue: thread writes out[nb+nn][w=wg*16+g4+r][m=half*8 .. +7]
    #pragma unroll
    for(int r=0;r<4;++r){
        float* op=base+(size_t)(nb+nn)*1024+(wg*16+g4+r)*16+half*8;
        ((float4*)op)[0]=make_float4(acc[r][0],acc[r][1],acc[r][2],acc[r][3]);
        ((float4*)op)[1]=make_float4(acc[r][4],acc[r][5],acc[r][6],acc[r][7]);
    }
}

extern "C" void kernel_launch(void* const* d_in, const int* in_sizes, int n_in,
                              void* d_out, int out_size, void* d_ws, size_t ws_size,
                              hipStream_t stream) {
    const float* node_attrs=(const float*)d_in[0];
    const float* node_feats=(const float*)d_in[1];
    const float* edge_attrs=(const float*)d_in[2];
    const float* edge_feats=(const float*)d_in[3];
    const int*   eidx_in  =(const int*)  d_in[4];
    const int*   sender   =eidx_in;
    const int*   recv     =eidx_in+N_EDGES;
    const float* mminv    =(const float*)d_in[5];
    const float* mattr    =(const float*)d_in[6];
    const float* wup      =(const float*)d_in[7];
    const float* wr0      =(const float*)d_in[8];
    const float* wr1      =(const float*)d_in[9];
    const float* wr2      =(const float*)d_in[10];
    const float* wr3      =(const float*)d_in[11];
    const float* wtr      =(const float*)d_in[12];
    const float* wdens    =(const float*)d_in[13];
    const float* wlin     =(const float*)d_in[14];
    const float* wmlin    =(const float*)d_in[15];
    const float* wskip    =(const float*)d_in[16];
    const float* wmskip   =(const float*)d_in[17];

    char* ws=(char*)d_ws;
    float*          x     =(float*)(ws+0);                      //  2 MB
    unsigned short* wxc   =(unsigned short*)(ws+2097152);       // 64 MB ([e][j][8] bf16)
    float*          ed    =(float*)(ws+73400320);               // 256 KB
    unsigned short* wtf   =(unsigned short*)(ws+73662464);      // 64 KB
    unsigned*       wwf   =(unsigned*)(ws+73728000);            //  2 MB
    unsigned short* w0f   =(unsigned short*)(ws+75825152);      //  4 KB
    unsigned short* w1f   =(unsigned short*)(ws+75829248);      //  8 KB
    unsigned short* w2f   =(unsigned short*)(ws+75837440);      //  8 KB
    int*            cnt   =(int*)(ws+75845632);                 // 32 KB
    int*            rowptr=(int*)(ws+75878400);                 // 32 KB + 4 (pad to 75911296)
    int*            cur   =(int*)(ws+75911296);                 // 32 KB
    int*            elist =(int*)(ws+75944064);                 // 256 KB -> 76206208
    if(ws_size < (size_t)76206208) return;   // insufficient scratch: fail loudly

    float* out=(float*)d_out;

    hipMemsetAsync(cnt,0,32768,stream);
    k_prep   <<<dim3(2900),dim3(256),0,stream>>>(node_feats,wup,x,
                                                 wr0,wr1,wr2,w0f,w1f,w2f,
                                                 wr3,wtr,wtf,
                                                 wlin,wmlin,wskip,wmskip,wwf,
                                                 recv,cnt);
    k_scan   <<<dim3(1),   dim3(1024),0,stream>>>(cnt,rowptr,cur);
    k_mid    <<<dim3(1280),dim3(256),0,stream>>>(recv,cur,elist,
                                                 edge_feats,mminv,sender,wdens,
                                                 (const uint4*)w0f,(const uint4*)w1f,
                                                 (const uint4*)w2f,(const uint4*)wtf,
                                                 x,wxc,ed);
    k_gather <<<dim3(2048),dim3(256),0,stream>>>(rowptr,elist,wxc,edge_attrs,mattr,sender,ed,out);
    k_final14<<<dim3(2048),dim3(256),0,stream>>>(node_attrs,wwf,out);
}

// Round 21
// 212.603 us; speedup vs baseline: 1.0125x; 1.0043x over previous
//
#include <hip/hip_runtime.h>

// Problem constants
#define N_NODES 8192
#define N_EDGES 65536

typedef __attribute__((ext_vector_type(8))) short bf16x8;
typedef __attribute__((ext_vector_type(4))) float f32x4;

// ---------- bf16 helpers (OCP bf16 = top 16 bits of f32, RNE) ----------
static __device__ __forceinline__ float bfl(unsigned v){ unsigned u=v<<16; float f; __builtin_memcpy(&f,&u,4); return f; }
static __device__ __forceinline__ float bfh(unsigned v){ unsigned u=v&0xffff0000u; float f; __builtin_memcpy(&f,&u,4); return f; }
static __device__ __forceinline__ unsigned short f2bf(float f){ unsigned u; __builtin_memcpy(&u,&f,4); u += 0x7fffu + ((u>>16)&1u); return (unsigned short)(u>>16); }
static __device__ __forceinline__ unsigned pk(float a, float b){ return (unsigned)f2bf(a) | ((unsigned)f2bf(b)<<16); }
static __device__ __forceinline__ float silu_f(float v){ return v/(1.f+__expf(-v)); }

// ---------- K_prep: fused {linup | wmlp | wtf(serial) | wwf | count} by block range ----------
__global__ __launch_bounds__(256) void k_prep(
    const float* __restrict__ nf,  const float* __restrict__ wup,  float* __restrict__ x,
    const float* __restrict__ wr0, const float* __restrict__ wr1,  const float* __restrict__ wr2,
    unsigned short* __restrict__ w0f, unsigned short* __restrict__ w1f, unsigned short* __restrict__ w2f,
    const float* __restrict__ wr3, const float* __restrict__ wtr,  unsigned short* __restrict__ wtf,
    const float* __restrict__ wlin, const float* __restrict__ wmlin,
    const float* __restrict__ wskip, const float* __restrict__ wmskip, unsigned* __restrict__ wwf,
    const int* __restrict__ recv, int* __restrict__ cnt)
{
    const int bid=blockIdx.x, t=threadIdx.x;
    if(bid<2048){
        // ---- linup: x = nf @ wup / 8 ----
        __shared__ float s[4][64];
        const int wv=t>>6, lane=t&63;
        const int n=bid*4+wv;
        s[wv][lane]=nf[(size_t)n*64+lane];
        __syncthreads();
        float acc=0.f;
        for(int c=0;c<64;++c) acc += s[wv][c]*wup[c*64+lane];
        x[(size_t)n*64+lane]=acc*0.125f;
    } else if(bid<2068){
        // ---- wmlp: MLP weight fragment tables ----
        const int b=bid-2048;
        #pragma unroll
        for(int z=0;z<2;++z){
            int idx=t*2+z;
            int lane=idx>>3, i=idx&7;
            if(b<4){
                int nt=b, k=(lane>>4)*8+i, n=nt*16+(lane&15);
                float v=(k<16)? wr0[k*64+n]*0.25f : 0.f;
                w0f[(nt*64+lane)*8+i]=f2bf(v);
            } else if(b<12){
                int q=b-4, nt=q>>1, ks=q&1;
                int k=ks*32+(lane>>4)*8+i, n=nt*16+(lane&15);
                w1f[((nt*2+ks)*64+lane)*8+i]=f2bf(wr1[k*64+n]*0.125f);
            } else {
                int q=b-12, nt=q>>1, ks=q&1;
                int k=ks*32+(lane>>4)*8+i, n=nt*16+(lane&15);
                w2f[((nt*2+ks)*64+lane)*8+i]=f2bf(wr2[k*64+n]*0.125f);
            }
        }
    } else if(bid<2132){
        // ---- wtf (serial GEMV variant; hidden under the other blocks) ----
        const int b=bid-2068;          // 0..63 = mt*2+ks
        const int mt=b>>1, ks=b&1;
        #pragma unroll
        for(int z=0;z<2;++z){
            int idx=t*2+z;
            int lane=idx>>3, i=idx&7;
            int k=ks*32+(lane>>4)*8+i;
            int n=mt*16+(lane&15);
            int j=n>>3, s=n&7;
            float v;
            if(s<4) v=wr3[k*256+s*64+j]*0.125f;
            else {
                float acc=0.f;
                for(int kk=0;kk<256;++kk) acc+=wr3[k*256+kk]*wtr[kk*256+(s-4)*64+j];
                v=acc*(1.f/128.f);
            }
            wtf[((size_t)b*64+lane)*8+i]=f2bf(v);
        }
    } else if(bid<2644){
        // ---- wwf: node-contraction fragment table ----
        const int b=bid-2132, ten=b>>8, lc=b&255, l=lc>>6, c=lc&63;
        const float* WL = ten? wmlin:wlin;
        const float* WS = ten? wmskip:wskip;
        const float scale = ten? (1.f/4096.f):(1.f/256.f);
        const int wg=t>>6, s=t&63, lane=s>>1, half=s&1;
        const int w=wg*16+(lane&15);
        const int v0=(lane>>4)*8+half*4;
        float a0=0,a1=0,a2=0,a3=0;
        for(int u=0;u<64;++u){
            float wl=WL[(l*64+c)*64+u];
            const float* wsp=&WS[(((l*64+u)*16+v0)*64)+w];
            a0+=wl*wsp[0]; a1+=wl*wsp[64]; a2+=wl*wsp[128]; a3+=wl*wsp[192];
        }
        size_t fi=(((size_t)ten*4+l)*64+c)*4+wg;
        unsigned* op=wwf + (fi*32+lane)*4 + half*2;
        op[0]=pk(a0*scale,a1*scale); op[1]=pk(a2*scale,a3*scale);
    } else {
        // ---- count ----
        int e=(bid-2644)*256+t;
        atomicAdd(&cnt[recv[e]],1);
    }
}

// ---------- k_scan ----------
__global__ __launch_bounds__(1024) void k_scan(const int* __restrict__ cnt, int* __restrict__ rowptr, int* __restrict__ cur){
    __shared__ int s[1024];
    const int t=threadIdx.x;
    int c[8]; int sum=0;
    #pragma unroll
    for(int i=0;i<8;++i){ c[i]=cnt[t*8+i]; sum+=c[i]; }
    s[t]=sum; __syncthreads();
    for(int off=1;off<1024;off<<=1){
        int v=s[t]; int add=(t>=off)? s[t-off]:0;
        __syncthreads();
        s[t]=v+add;
        __syncthreads();
    }
    int run=s[t]-sum;
    #pragma unroll
    for(int i=0;i<8;++i){ rowptr[t*8+i]=run; cur[t*8+i]=run; run+=c[i]; }
    if(t==1023) rowptr[8192]=run;
}

// ---------- K_mid: fused {scatter | edge2} by block range ----------
__global__ __launch_bounds__(256) void k_mid(
    const int* __restrict__ recv, int* __restrict__ cur, int* __restrict__ elist,
    const float* __restrict__ ef, const float* __restrict__ mminv,
    const int* __restrict__ sender,
    const float* __restrict__ wdens,
    const uint4* __restrict__ w0f, const uint4* __restrict__ w1f,
    const uint4* __restrict__ w2f, const uint4* __restrict__ wtf,
    const float* __restrict__ x,
    unsigned short* __restrict__ wxc, float* __restrict__ ed)
{
    __shared__ unsigned short hA[4096];   // 8KB  [e][k] bf16 swizzled
    __shared__ unsigned short hB[4096];   // 8KB
    __shared__ float xs[64*68];           // 17KB [e][j pad 68]
    const int bid=blockIdx.x, t=threadIdx.x;
    if(bid<256){
        // ---- scatter ----
        int e=bid*256+t;
        int r=recv[e];
        int p=atomicAdd(&cur[r],1);
        elist[p]=e;
        return;
    }
    // ---- edge2 ----
    const int lane=t&63, wv=t>>6;
    const int tile=(bid-256)*64;

    {
        const int e=t>>2, q=t&3, ge=tile+e;
        const int s=sender[ge];
        const float4* xp=(const float4*)(x+(size_t)s*64+q*16);
        float4* xw=(float4*)&xs[e*68+q*16];
        xw[0]=xp[0]; xw[1]=xp[1]; xw[2]=xp[2]; xw[3]=xp[3];
        const int se3=(e&7)<<3;
        if(q==0){
            float4 f0=*(const float4*)(ef+(size_t)ge*8);
            float4 f1=*(const float4*)(ef+(size_t)ge*8+4);
            uint4 o; o.x=pk(f0.x,f0.y); o.y=pk(f0.z,f0.w); o.z=pk(f1.x,f1.y); o.w=pk(f1.z,f1.w);
            *(uint4*)&hA[e*64 + (0^se3)]=o;
            float acc=f0.x*wdens[0]+f0.y*wdens[1]+f0.z*wdens[2]+f0.w*wdens[3]
                     +f1.x*wdens[4]+f1.y*wdens[5]+f1.z*wdens[6]+f1.w*wdens[7];
            acc*=0.35355339059327373f;           // 1/sqrt(8)
            float q2=acc*acc;
            float ex=__expf(2.f*q2);
            ed[ge]=1.f-2.f/(ex+1.f);             // tanh(q2)
        } else if(q==1){
            float4 f0=*(const float4*)(mminv+(size_t)s*8);
            float4 f1=*(const float4*)(mminv+(size_t)s*8+4);
            uint4 o; o.x=pk(f0.x,f0.y); o.y=pk(f0.z,f0.w); o.z=pk(f1.x,f1.y); o.w=pk(f1.z,f1.w);
            *(uint4*)&hA[e*64 + (8^se3)]=o;
        } else if(q==2){
            *(uint4*)&hA[e*64 + (16^se3)]=make_uint4(0,0,0,0);
        } else {
            *(uint4*)&hA[e*64 + (24^se3)]=make_uint4(0,0,0,0);
        }
    }
    __syncthreads();

    const int arow=wv*16+(lane&15);
    const int akg=lane>>4;
    const int aswz=(arow&7)<<3;
    const int dcol=lane&15;
    const int drow0=wv*16+(lane>>4)*4;

    // ---- L1 ----
    {
        uint4 av=*(const uint4*)&hA[arow*64+((akg*8)^aswz)];
        bf16x8 a; __builtin_memcpy(&a,&av,16);
        f32x4 d[4];
        #pragma unroll
        for(int nt=0;nt<4;++nt){
            uint4 bw=w0f[nt*64+lane];
            bf16x8 b; __builtin_memcpy(&b,&bw,16);
            f32x4 z={0.f,0.f,0.f,0.f};
            d[nt]=__builtin_amdgcn_mfma_f32_16x16x32_bf16(a,b,z,0,0,0);
        }
        #pragma unroll
        for(int nt=0;nt<4;++nt){
            #pragma unroll
            for(int r=0;r<4;++r){
                int e2=drow0+r, n=nt*16+dcol;
                hB[e2*64 + (n^((e2&7)<<3))]=f2bf(silu_f(d[nt][r]));
            }
        }
    }
    __syncthreads();

    // ---- L2 ----
    {
        uint4 av0=*(const uint4*)&hB[arow*64+(((0+akg)*8)^aswz)];
        uint4 av1=*(const uint4*)&hB[arow*64+(((4+akg)*8)^aswz)];
        bf16x8 a0,a1; __builtin_memcpy(&a0,&av0,16); __builtin_memcpy(&a1,&av1,16);
        f32x4 d[4];
        #pragma unroll
        for(int nt=0;nt<4;++nt){
            uint4 bw0=w1f[(nt*2+0)*64+lane];
            uint4 bw1=w1f[(nt*2+1)*64+lane];
            bf16x8 b0,b1; __builtin_memcpy(&b0,&bw0,16); __builtin_memcpy(&b1,&bw1,16);
            f32x4 z={0.f,0.f,0.f,0.f};
            d[nt]=__builtin_amdgcn_mfma_f32_16x16x32_bf16(a0,b0,z,0,0,0);
            d[nt]=__builtin_amdgcn_mfma_f32_16x16x32_bf16(a1,b1,d[nt],0,0,0);
        }
        #pragma unroll
        for(int nt=0;nt<4;++nt){
            #pragma unroll
            for(int r=0;r<4;++r){
                int e2=drow0+r, n=nt*16+dcol;
                hA[e2*64 + (n^((e2&7)<<3))]=f2bf(silu_f(d[nt][r]));
            }
        }
    }
    __syncthreads();

    // ---- L3 ----
    {
        uint4 av0=*(const uint4*)&hA[arow*64+(((0+akg)*8)^aswz)];
        uint4 av1=*(const uint4*)&hA[arow*64+(((4+akg)*8)^aswz)];
        bf16x8 a0,a1; __builtin_memcpy(&a0,&av0,16); __builtin_memcpy(&a1,&av1,16);
        f32x4 d[4];
        #pragma unroll
        for(int nt=0;nt<4;++nt){
            uint4 bw0=w2f[(nt*2+0)*64+lane];
            uint4 bw1=w2f[(nt*2+1)*64+lane];
            bf16x8 b0,b1; __builtin_memcpy(&b0,&bw0,16); __builtin_memcpy(&b1,&bw1,16);
            f32x4 z={0.f,0.f,0.f,0.f};
            d[nt]=__builtin_amdgcn_mfma_f32_16x16x32_bf16(a0,b0,z,0,0,0);
            d[nt]=__builtin_amdgcn_mfma_f32_16x16x32_bf16(a1,b1,d[nt],0,0,0);
        }
        #pragma unroll
        for(int nt=0;nt<4;++nt){
            #pragma unroll
            for(int r=0;r<4;++r){
                int e2=drow0+r, n=nt*16+dcol;
                hB[e2*64 + (n^((e2&7)<<3))]=f2bf(silu_f(d[nt][r]));
            }
        }
    }
    __syncthreads();

    // ---- phase B ----
    {
        bf16x8 hb[4][2];
        #pragma unroll
        for(int nt2=0;nt2<4;++nt2){
            int erow=nt2*16+(lane&15);
            int esz=(erow&7)<<3;
            #pragma unroll
            for(int ks=0;ks<2;++ks){
                uint4 v=*(const uint4*)&hB[erow*64+(((ks*4+akg)*8)^esz)];
                __builtin_memcpy(&hb[nt2][ks],&v,16);
            }
        }
        const int g=lane>>4;
        const int jo=g>>1, sh=g&1;
        for(int mt=0;mt<8;++mt){
            int mtg=wv*8+mt;
            uint4 aw0=wtf[(mtg*2+0)*64+lane];
            uint4 aw1=wtf[(mtg*2+1)*64+lane];
            bf16x8 a0,a1; __builtin_memcpy(&a0,&aw0,16); __builtin_memcpy(&a1,&aw1,16);
            int j=mtg*2+jo;
            #pragma unroll
            for(int nt2=0;nt2<4;++nt2){
                f32x4 z={0.f,0.f,0.f,0.f};
                f32x4 d=__builtin_amdgcn_mfma_f32_16x16x32_bf16(a0,hb[nt2][0],z,0,0,0);
                d=__builtin_amdgcn_mfma_f32_16x16x32_bf16(a1,hb[nt2][1],d,0,0,0);
                int eloc=nt2*16+(lane&15);
                float xj=xs[eloc*68+j];
                uint2 o; o.x=pk(d[0]*xj,d[1]*xj); o.y=pk(d[2]*xj,d[3]*xj);
                *(uint2*)&wxc[((size_t)(tile+eloc)*64+j)*8+sh*4]=o;
            }
        }
    }
}

// ---------- K3: wave-per-node gather; writes msgd (msg/(1+D)) and mm_raw into d_out
__global__ __launch_bounds__(256) void k_gather(
    const int* __restrict__ rowptr, const int* __restrict__ elist,
    const unsigned short* __restrict__ wxc, const float* __restrict__ ea,
    const float* __restrict__ mattr, const int* __restrict__ sender,
    const float* __restrict__ ed,
    float* __restrict__ out)
{
    const int t=threadIdx.x, wv=t>>6, lane=t&63;
    const int n=blockIdx.x*4+wv;
    const int r0=rowptr[n], r1=rowptr[n+1];
    float msg[16]; float mm[16];
    #pragma unroll
    for(int m=0;m<16;++m){ msg[m]=0.f; mm[m]=0.f; }
    float dens=0.f;
    for(int k=r0;k<r1;++k){
        int e=elist[k];
        uint4 r=*(const uint4*)(wxc+((size_t)e*64+lane)*8);
        int s=sender[e];
        float wx0=bfl(r.x),wx1=bfh(r.x),wx2=bfl(r.y),wx3=bfh(r.y);
        float wm0=bfl(r.z),wm1=bfh(r.z),wm2=bfl(r.w),wm3=bfh(r.w);
        dens+=ed[e];
        const float4* eap=(const float4*)(ea+(size_t)e*16);
        const float4* map=(const float4*)(mattr+(size_t)s*16);
        float4 A0=eap[0],A1=eap[1],A2=eap[2],A3=eap[3];
        float4 B0=map[0],B1=map[1],B2=map[2],B3=map[3];
        msg[0]+=wx0*A0.x;
        msg[1]+=wx1*A0.y;  msg[2]+=wx1*A0.z;  msg[3]+=wx1*A0.w;
        msg[4]+=wx2*A1.x;  msg[5]+=wx2*A1.y;  msg[6]+=wx2*A1.z;  msg[7]+=wx2*A1.w;  msg[8]+=wx2*A2.x;
        msg[9]+=wx3*A2.y;  msg[10]+=wx3*A2.z; msg[11]+=wx3*A2.w;
        msg[12]+=wx3*A3.x; msg[13]+=wx3*A3.y; msg[14]+=wx3*A3.z; msg[15]+=wx3*A3.w;
        mm[0]+=wm0*B0.x;
        mm[1]+=wm1*B0.y;  mm[2]+=wm1*B0.z;  mm[3]+=wm1*B0.w;
        mm[4]+=wm2*B1.x;  mm[5]+=wm2*B1.y;  mm[6]+=wm2*B1.z;  mm[7]+=wm2*B1.w;  mm[8]+=wm2*B2.x;
        mm[9]+=wm3*B2.y;  mm[10]+=wm3*B2.z; mm[11]+=wm3*B2.w;
        mm[12]+=wm3*B3.x; mm[13]+=wm3*B3.y; mm[14]+=wm3*B3.z; mm[15]+=wm3*B3.w;
    }
    float inv=1.f/(1.f+dens);
    float* mp=out+(size_t)n*1024+lane*16;
    ((float4*)mp)[0]=make_float4(msg[0]*inv,msg[1]*inv,msg[2]*inv,msg[3]*inv);
    ((float4*)mp)[1]=make_float4(msg[4]*inv,msg[5]*inv,msg[6]*inv,msg[7]*inv);
    ((float4*)mp)[2]=make_float4(msg[8]*inv,msg[9]*inv,msg[10]*inv,msg[11]*inv);
    ((float4*)mp)[3]=make_float4(msg[12]*inv,msg[13]*inv,msg[14]*inv,msg[15]*inv);
    float* qp=out+8388608+(size_t)n*1024+lane*16;
    ((float4*)qp)[0]=make_float4(mm[0],mm[1],mm[2],mm[3]);
    ((float4*)qp)[1]=make_float4(mm[4],mm[5],mm[6],mm[7]);
    ((float4*)qp)[2]=make_float4(mm[8],mm[9],mm[10],mm[11]);
    ((float4*)qp)[3]=make_float4(mm[12],mm[13],mm[14],mm[15]);
}

// ---------- K4 v10 (best measured, R16): TRANSPOSED MFMA — D[w][n] instead of D[n][w].
// mfma(wwfFrag as A, attrsFrag as B): A[w][v], B[v][n] -> D[w=g4+r][n=lane&15] = Wn[n,c,w].
// Thread owns ONE node => msg reads are r-invariant: 2 ds_read_b128 per c.
#define TSTEP0_(v0,v1,v2, cc) { \
    const float* rp_=&msgSf[((cc)*16+nn)*8]; \
    float4 fa_=*(const float4*)(rp_+swsel); \
    float4 fb_=*(const float4*)(rp_+(4-swsel)); \
    _Pragma("unroll") \
    for(int r_=0;r_<4;++r_){ \
        acc[r_][0]+=fa_.x*v0[r_]; \
        acc[r_][1]+=fa_.y*v1[r_]; \
        acc[r_][2]+=fa_.z*v1[r_]; \
        acc[r_][3]+=fa_.w*v1[r_]; \
        acc[r_][4]+=fb_.x*v2[r_]; \
        acc[r_][5]+=fb_.y*v2[r_]; \
        acc[r_][6]+=fb_.z*v2[r_]; \
        acc[r_][7]+=fb_.w*v2[r_]; \
    } }
#define TSTEP1_(v0,v1, cc) { \
    const float* rp_=&msgSf[((cc)*16+nn)*8]; \
    float4 fa_=*(const float4*)(rp_+swsel); \
    float4 fb_=*(const float4*)(rp_+(4-swsel)); \
    _Pragma("unroll") \
    for(int r_=0;r_<4;++r_){ \
        acc[r_][0]+=fa_.x*v0[r_]; \
        acc[r_][1]+=fa_.y*v1[r_]; \
        acc[r_][2]+=fa_.z*v1[r_]; \
        acc[r_][3]+=fa_.w*v1[r_]; \
        acc[r_][4]+=fb_.x*v1[r_]; \
        acc[r_][5]+=fb_.y*v1[r_]; \
        acc[r_][6]+=fb_.z*v1[r_]; \
        acc[r_][7]+=fb_.w*v1[r_]; \
    } }
#define MFMA1T_(o, b) { \
    bf16x8 f_; __builtin_memcpy(&f_,&(b),16); \
    f32x4 z_={0.f,0.f,0.f,0.f}; \
    o=__builtin_amdgcn_mfma_f32_16x16x32_bf16(f_,afrag,z_,0,0,0); }

__global__ __launch_bounds__(256) void k_final10(const float* __restrict__ attrs,
                                                 const unsigned* __restrict__ wwf,
                                                 float* __restrict__ out){
    __shared__ float msgSf[64*16*8];   // [c][n][8m] f32, 32768 B (half-swap swizzled)
    const int blk=blockIdx.x;
    const int half=blk&1;
    const int rest=blk>>1;
    const int ten=rest>>9, nb=(rest&511)*16;
    float* base=out+(size_t)ten*8388608;
    const int t=threadIdx.x, lane=t&63, wg=t>>6;

    // stage msg half-slab (f32 [n][c][m]) -> msgSf [c][n][8] (f32, swizzled halves)
    const float4* src=(const float4*)(base+(size_t)nb*1024);
    #pragma unroll
    for(int i=0;i<8;++i){
        int tau=i*256+t;
        int n=tau>>7, rem=tau&127, c=rem>>1, qq=rem&1;
        float4 f=src[(n<<8)+(c<<2)+half*2+qq];
        int slot=qq^((n>>2)&1);
        *(float4*)&msgSf[(c*16+n)*8+slot*4]=f;
    }
    // attrs B-fragment: B[v=(lane>>4)*8+i][n=lane&15] = attrs[nb+n][v]  (zero for v>=16)
    bf16x8 afrag;
    {
        int nloc=lane&15, kg=lane>>4;
        if(kg<2){
            const float* ap=attrs+(size_t)(nb+nloc)*16+kg*8;
            #pragma unroll
            for(int i=0;i<8;++i) afrag[i]=(short)f2bf(ap[i]);
        } else {
            #pragma unroll
            for(int i=0;i<8;++i) afrag[i]=0;
        }
    }
    __syncthreads();

    const int nn=lane&15;              // thread's node (D col)
    const int g4=(lane>>4)*4;          // thread's first w-row (D row base)
    const int swsel=((nn>>2)&1)*4;     // msg half-swap select (floats)
    float acc[4][8];
    #pragma unroll
    for(int r=0;r<4;++r)
        #pragma unroll
        for(int m=0;m<8;++m) acc[r][m]=0.f;

    const uint4* wwf4=(const uint4*)wwf;
    const int l31=lane&31;

    if(half==0){
        const uint4* p0=wwf4+((size_t)((ten*4+0)*64)*4+wg)*32+l31;
        const uint4* p1=wwf4+((size_t)((ten*4+1)*64)*4+wg)*32+l31;
        const uint4* p2=wwf4+((size_t)((ten*4+2)*64)*4+wg)*32+l31;
        uint4 A0=p0[0], A1=p1[0], A2=p2[0];
        uint4 B0=p0[128], B1=p1[128], B2=p2[128];
        f32x4 dA0,dA1,dA2, dB0,dB1,dB2;
        MFMA1T_(dA0,A0); MFMA1T_(dA1,A1); MFMA1T_(dA2,A2);
        for(int c=0;c<64;c+=2){
            const int cA=(c+2<64)? c+2 : 63;
            const int cB=(c+3<64)? c+3 : 63;
            A0=p0[cA*128]; A1=p1[cA*128]; A2=p2[cA*128];
            MFMA1T_(dB0,B0); MFMA1T_(dB1,B1); MFMA1T_(dB2,B2);
            TSTEP0_(dA0,dA1,dA2, c);
            B0=p0[cB*128]; B1=p1[cB*128]; B2=p2[cB*128];
            MFMA1T_(dA0,A0); MFMA1T_(dA1,A1); MFMA1T_(dA2,A2);
            TSTEP0_(dB0,dB1,dB2, c+1);
        }
    } else {
        const uint4* p0=wwf4+((size_t)((ten*4+2)*64)*4+wg)*32+l31;
        const uint4* p1=wwf4+((size_t)((ten*4+3)*64)*4+wg)*32+l31;
        uint4 A0=p0[0], A1=p1[0];
        uint4 B0=p0[128], B1=p1[128];
        f32x4 dA0,dA1, dB0,dB1;
        MFMA1T_(dA0,A0); MFMA1T_(dA1,A1);
        for(int c=0;c<64;c+=2){
            const int cA=(c+2<64)? c+2 : 63;
            const int cB=(c+3<64)? c+3 : 63;
            A0=p0[cA*128]; A1=p1[cA*128];
            MFMA1T_(dB0,B0); MFMA1T_(dB1,B1);
            TSTEP1_(dA0,dA1, c);
            B0=p0[cB*128]; B1=p1[cB*128];
            MFMA1T_(dA0,A0); MFMA1T_(dA1,A1);
            TSTEP1_(dB0,dB1, c+1);
        }
    }

    // epilogue: thread writes out[nb+nn][w=wg*16+g4+r][m=half*8 .. +7]
    #pragma unroll
    for(int r=0;r<4;++r){
        float* op=base+(size_t)(nb+nn)*1024+(wg*16+g4+r)*16+half*8;
        ((float4*)op)[0]=make_float4(acc[r][0],acc[r][1],acc[r][2],acc[r][3]);
        ((float4*)op)[1]=make_float4(acc[r][4],acc[r][5],acc[r][6],acc[r][7]);
    }
}

extern "C" void kernel_launch(void* const* d_in, const int* in_sizes, int n_in,
                              void* d_out, int out_size, void* d_ws, size_t ws_size,
                              hipStream_t stream) {
    const float* node_attrs=(const float*)d_in[0];
    const float* node_feats=(const float*)d_in[1];
    const float* edge_attrs=(const float*)d_in[2];
    const float* edge_feats=(const float*)d_in[3];
    const int*   eidx_in  =(const int*)  d_in[4];
    const int*   sender   =eidx_in;
    const int*   recv     =eidx_in+N_EDGES;
    const float* mminv    =(const float*)d_in[5];
    const float* mattr    =(const float*)d_in[6];
    const float* wup      =(const float*)d_in[7];
    const float* wr0      =(const float*)d_in[8];
    const float* wr1      =(const float*)d_in[9];
    const float* wr2      =(const float*)d_in[10];
    const float* wr3      =(const float*)d_in[11];
    const float* wtr      =(const float*)d_in[12];
    const float* wdens    =(const float*)d_in[13];
    const float* wlin     =(const float*)d_in[14];
    const float* wmlin    =(const float*)d_in[15];
    const float* wskip    =(const float*)d_in[16];
    const float* wmskip   =(const float*)d_in[17];

    char* ws=(char*)d_ws;
    float*          x     =(float*)(ws+0);                      //  2 MB
    unsigned short* wxc   =(unsigned short*)(ws+2097152);       // 64 MB ([e][j][8] bf16)
    float*          ed    =(float*)(ws+73400320);               // 256 KB
    unsigned short* wtf   =(unsigned short*)(ws+73662464);      // 64 KB
    unsigned*       wwf   =(unsigned*)(ws+73728000);            //  2 MB
    unsigned short* w0f   =(unsigned short*)(ws+75825152);      //  4 KB
    unsigned short* w1f   =(unsigned short*)(ws+75829248);      //  8 KB
    unsigned short* w2f   =(unsigned short*)(ws+75837440);      //  8 KB
    int*            cnt   =(int*)(ws+75845632);                 // 32 KB
    int*            rowptr=(int*)(ws+75878400);                 // 32 KB + 4 (pad to 75911296)
    int*            cur   =(int*)(ws+75911296);                 // 32 KB
    int*            elist =(int*)(ws+75944064);                 // 256 KB -> 76206208
    if(ws_size < (size_t)76206208) return;   // insufficient scratch: fail loudly

    float* out=(float*)d_out;

    hipMemsetAsync(cnt,0,32768,stream);
    k_prep   <<<dim3(2900),dim3(256),0,stream>>>(node_feats,wup,x,
                                                 wr0,wr1,wr2,w0f,w1f,w2f,
                                                 wr3,wtr,wtf,
                                                 wlin,wmlin,wskip,wmskip,wwf,
                                                 recv,cnt);
    k_scan   <<<dim3(1),   dim3(1024),0,stream>>>(cnt,rowptr,cur);
    k_mid    <<<dim3(1280),dim3(256),0,stream>>>(recv,cur,elist,
                                                 edge_feats,mminv,sender,wdens,
                                                 (const uint4*)w0f,(const uint4*)w1f,
                                                 (const uint4*)w2f,(const uint4*)wtf,
                                                 x,wxc,ed);
    k_gather <<<dim3(2048),dim3(256),0,stream>>>(rowptr,elist,wxc,edge_attrs,mattr,sender,ed,out);
    k_final10<<<dim3(2048),dim3(256),0,stream>>>(node_attrs,wwf,out);
}